// Round 1
// baseline (282.615 us; speedup 1.0000x reference)
//
#include <hip/hip_runtime.h>
#include <hip/hip_bf16.h>
#include <math.h>

#define ENTITY_STRIDE 64
#define LOOP_LEN 50

__global__ void BoxNetwork_40802189312698_kernel(const int* __restrict__ index_vec,
                                                 const int* __restrict__ neighbor_index_vec,
                                                 const float* __restrict__ len_sum_p,
                                                 const float* __restrict__ emb,
                                                 float* __restrict__ out) {
    const int lane = threadIdx.x;  // single wave of 64

    // indices fit in 32 bits; read low word (valid for int32 or little-endian int64)
    const long long i = (long long)index_vec[0];
    const long long j = (long long)neighbor_index_vec[0];

    float d = 1e30f;
    if (lane < LOOP_LEN) {
        const float c = emb[i * ENTITY_STRIDE + lane];
        const float n = emb[j * ENTITY_STRIDE + lane];
        d = fabsf(c - n);
    }

    // 64-lane butterfly min-reduce
    #pragma unroll
    for (int off = 32; off > 0; off >>= 1) {
        d = fminf(d, __shfl_down(d, off, 64));
    }

    if (lane == 0) {
        const float ls = len_sum_p[0];
        const float l1 = fabsf(d - ls);
        out[0] = (d < ls) ? (100.0f * l1) : l1;
    }
}

extern "C" void kernel_launch(void* const* d_in, const int* in_sizes, int n_in,
                              void* d_out, int out_size, void* d_ws, size_t ws_size,
                              hipStream_t stream) {
    const int*   index_vec          = (const int*)d_in[0];
    const int*   neighbor_index_vec = (const int*)d_in[1];
    const float* len_sum            = (const float*)d_in[2];
    const float* emb                = (const float*)d_in[3];
    float*       out                = (float*)d_out;

    BoxNetwork_40802189312698_kernel<<<1, 64, 0, stream>>>(
        index_vec, neighbor_index_vec, len_sum, emb, out);
}